// Round 1
// baseline (284.562 us; speedup 1.0000x reference)
//
#include <hip/hip_runtime.h>

typedef _Float16 half8 __attribute__((ext_vector_type(8)));
typedef float floatx4 __attribute__((ext_vector_type(4)));

#define INV_TEMP 0.08838834764831845f

// workspace layout (bytes)
#define OFF_WT 0                          // 3 * 128 * 1024 f16 = 786432 B
#define OFF_QS (786432)                   // 16384*128 f16 = 4 MiB
#define OFF_KS (786432 + 4194304)
#define OFF_VT (786432 + 2 * 4194304)     // vt[b][dv][key] transposed

// ---------------- weight prep: wt[m][n][k] = W_m[k][n] (* 1/temp for m==0) ----
__global__ __launch_bounds__(256) void wprep_kernel(
    const float* __restrict__ Wq, const float* __restrict__ Wk,
    const float* __restrict__ Wv, _Float16* __restrict__ wt)
{
    int idx = blockIdx.x * 256 + threadIdx.x;   // 0 .. 393215
    int m = idx >> 17;
    int rem = idx & 131071;
    int n = rem >> 10;
    int kk = rem & 1023;
    const float* W = (m == 0) ? Wq : (m == 1) ? Wk : Wv;
    float val = W[kk * 128 + n];
    if (m == 0) val *= INV_TEMP;
    wt[idx] = (_Float16)val;
}

// ---------------- fused QKV projection: X[16384,1024] @ W -> f16 -------------
// grid (256, 3); block 256 (4 waves). Tile: 64 rows x 128 cols, BK=64.
__global__ __launch_bounds__(256) void proj_kernel(
    const float* __restrict__ Xq, const float* __restrict__ Xk,
    const float* __restrict__ Xv, const _Float16* __restrict__ wt,
    _Float16* __restrict__ qs, _Float16* __restrict__ ks,
    _Float16* __restrict__ vt)
{
    __shared__ _Float16 smem[64 * 72 + 128 * 72];
    _Float16* As = smem;            // [64][72]  (pad 8 -> 2-way bank alias only)
    _Float16* Bs = smem + 64 * 72;  // [128][72]

    const int t = threadIdx.x;
    const int lane = t & 63;
    const int w = t >> 6;
    const int quad = lane >> 4;
    const int m16 = lane & 15;
    const int yb = blockIdx.y;
    const float* X = (yb == 0) ? Xq : (yb == 1) ? Xk : Xv;
    const _Float16* W = wt + yb * 131072;   // [128][1024]
    const int m0 = blockIdx.x * 64;

    floatx4 acc[8] = {};

    const int arow = t >> 2, ac4 = t & 3;   // A staging: 4 thr/row, 16 floats
    const int bn = t >> 1, bh = t & 1;      // B staging: 2 thr/row, 32 f16

    for (int k0 = 0; k0 < 1024; k0 += 64) {
        {   // stage A tile (fp32 -> f16)
            const float* src = X + (size_t)(m0 + arow) * 1024 + k0 + ac4 * 16;
            float4 f0 = ((const float4*)src)[0];
            float4 f1 = ((const float4*)src)[1];
            float4 f2 = ((const float4*)src)[2];
            float4 f3 = ((const float4*)src)[3];
            _Float16* dst = As + arow * 72 + ac4 * 16;
            half8 h0 = {(_Float16)f0.x, (_Float16)f0.y, (_Float16)f0.z, (_Float16)f0.w,
                        (_Float16)f1.x, (_Float16)f1.y, (_Float16)f1.z, (_Float16)f1.w};
            half8 h1 = {(_Float16)f2.x, (_Float16)f2.y, (_Float16)f2.z, (_Float16)f2.w,
                        (_Float16)f3.x, (_Float16)f3.y, (_Float16)f3.z, (_Float16)f3.w};
            *(half8*)(dst) = h0;
            *(half8*)(dst + 8) = h1;
        }
        {   // stage B tile (already f16, [n][k] layout)
            const _Float16* src = W + bn * 1024 + k0 + bh * 32;
            _Float16* dst = Bs + bn * 72 + bh * 32;
            #pragma unroll
            for (int i = 0; i < 4; i++)
                *(half8*)(dst + 8 * i) = ((const half8*)src)[i];
        }
        __syncthreads();

        #pragma unroll
        for (int kk = 0; kk < 64; kk += 32) {
            half8 a = *(const half8*)(As + (w * 16 + m16) * 72 + kk + quad * 8);
            #pragma unroll
            for (int nt = 0; nt < 8; nt++) {
                half8 b = *(const half8*)(Bs + (nt * 16 + m16) * 72 + kk + quad * 8);
                acc[nt] = __builtin_amdgcn_mfma_f32_16x16x32_f16(a, b, acc[nt], 0, 0, 0);
            }
        }
        __syncthreads();
    }

    if (yb < 2) {
        // qs/ks: row-major [row][128]
        _Float16* out = (yb == 0) ? qs : ks;
        #pragma unroll
        for (int nt = 0; nt < 8; nt++) {
            #pragma unroll
            for (int r = 0; r < 4; r++) {
                int row = m0 + w * 16 + quad * 4 + r;
                out[(size_t)row * 128 + nt * 16 + m16] = (_Float16)acc[nt][r];
            }
        }
    } else {
        // vs: transpose via LDS -> vt[b][dv][key]
        _Float16* T = smem;   // [64][130]
        #pragma unroll
        for (int nt = 0; nt < 8; nt++) {
            #pragma unroll
            for (int r = 0; r < 4; r++)
                T[(w * 16 + quad * 4 + r) * 130 + nt * 16 + m16] = (_Float16)acc[nt][r];
        }
        __syncthreads();
        int dv = t >> 1, hf = t & 1;
        int bb = m0 >> 11;
        int key0 = (m0 & 2047) + hf * 32;
        _Float16* dst = vt + (size_t)(bb * 128 + dv) * 2048 + key0;
        #pragma unroll
        for (int j8 = 0; j8 < 4; j8++) {
            half8 h;
            #pragma unroll
            for (int j = 0; j < 8; j++)
                h[j] = T[(hf * 32 + j8 * 8 + j) * 130 + dv];
            *(half8*)(dst + j8 * 8) = h;
        }
    }
}

// ---------------- flash attention ------------------------------------------
// grid (32, 8); block 256 (4 waves). 64 q-rows/block, KT=64 keys/iter.
__global__ __launch_bounds__(256) void attn_kernel(
    const _Float16* __restrict__ qs, const _Float16* __restrict__ ks,
    const _Float16* __restrict__ vt, const int* __restrict__ mlen,
    float* __restrict__ out)
{
    __shared__ _Float16 kls[64 * 136];      // [key][136]
    __shared__ _Float16 vls[128 * 72];      // [dv][72]
    __shared__ _Float16 pls[4 * 16 * 72];   // per-wave [16][72]

    const int t = threadIdx.x;
    const int lane = t & 63;
    const int w = t >> 6;
    const int quad = lane >> 4;
    const int m16 = lane & 15;
    const int b = blockIdx.y;
    const int q0 = blockIdx.x * 64;
    const int ml = mlen[b];
    const int nkt = (ml + 63) >> 6;         // skip fully-masked key tiles

    // preload Q A-fragments (held in regs across the whole key loop)
    half8 aq[4];
    {
        const _Float16* qrow =
            qs + (size_t)(b * 2048 + q0 + w * 16 + m16) * 128 + quad * 8;
        #pragma unroll
        for (int d = 0; d < 4; d++)
            aq[d] = *(const half8*)(qrow + d * 32);
    }

    floatx4 acc[8] = {};
    float m_i[4] = {-3e38f, -3e38f, -3e38f, -3e38f};
    float l_i[4] = {0.f, 0.f, 0.f, 0.f};

    const int skey = t >> 2, sq4 = t & 3;   // ks staging
    const int sdv = t >> 1, shf = t & 1;    // vt staging

    for (int kt = 0; kt < nkt; kt++) {
        const int k0 = kt * 64;
        {   // stage K tile [64 key][128 d]
            const _Float16* src = ks + (size_t)(b * 2048 + k0 + skey) * 128 + sq4 * 32;
            _Float16* dst = kls + skey * 136 + sq4 * 32;
            #pragma unroll
            for (int i = 0; i < 4; i++)
                *(half8*)(dst + 8 * i) = ((const half8*)src)[i];
        }
        {   // stage V^T tile [128 dv][64 key]
            const _Float16* src = vt + (size_t)(b * 128 + sdv) * 2048 + k0 + shf * 32;
            _Float16* dst = vls + sdv * 72 + shf * 32;
            #pragma unroll
            for (int i = 0; i < 4; i++)
                *(half8*)(dst + 8 * i) = ((const half8*)src)[i];
        }
        __syncthreads();

        // S = (Q/temp) K^T : 16 q x 64 key per wave
        floatx4 sacc[4] = {};
        #pragma unroll
        for (int d = 0; d < 4; d++) {
            #pragma unroll
            for (int nt = 0; nt < 4; nt++) {
                half8 bfrag = *(const half8*)(kls + (nt * 16 + m16) * 136 + d * 32 + quad * 8);
                sacc[nt] = __builtin_amdgcn_mfma_f32_16x16x32_f16(aq[d], bfrag, sacc[nt], 0, 0, 0);
            }
        }

        // mask + online softmax (rows = quad*4+r, cols spread over 16 lanes)
        float p[4][4];
        float rowmax[4], rowsum[4];
        #pragma unroll
        for (int r = 0; r < 4; r++) rowmax[r] = -3e38f;
        #pragma unroll
        for (int nt = 0; nt < 4; nt++) {
            int key = k0 + nt * 16 + m16;
            bool valid = key < ml;
            #pragma unroll
            for (int r = 0; r < 4; r++) {
                float s = valid ? sacc[nt][r] : -3e38f;
                p[nt][r] = s;
                rowmax[r] = fmaxf(rowmax[r], s);
            }
        }
        #pragma unroll
        for (int mask = 8; mask >= 1; mask >>= 1) {
            #pragma unroll
            for (int r = 0; r < 4; r++)
                rowmax[r] = fmaxf(rowmax[r], __shfl_xor(rowmax[r], mask, 64));
        }
        #pragma unroll
        for (int r = 0; r < 4; r++) {
            float mnew = fmaxf(m_i[r], rowmax[r]);
            float alpha = __expf(m_i[r] - mnew);
            m_i[r] = mnew;
            l_i[r] *= alpha;
            #pragma unroll
            for (int nt = 0; nt < 8; nt++) acc[nt][r] *= alpha;
            rowsum[r] = 0.f;
            #pragma unroll
            for (int nt = 0; nt < 4; nt++) {
                float e = __expf(p[nt][r] - mnew);
                p[nt][r] = e;
                rowsum[r] += e;
            }
        }
        #pragma unroll
        for (int mask = 8; mask >= 1; mask >>= 1) {
            #pragma unroll
            for (int r = 0; r < 4; r++)
                rowsum[r] += __shfl_xor(rowsum[r], mask, 64);
        }
        #pragma unroll
        for (int r = 0; r < 4; r++) l_i[r] += rowsum[r];

        // P: C-layout -> A-layout via per-wave LDS round-trip
        _Float16* pw = pls + w * 16 * 72;
        #pragma unroll
        for (int nt = 0; nt < 4; nt++) {
            #pragma unroll
            for (int r = 0; r < 4; r++)
                pw[(quad * 4 + r) * 72 + nt * 16 + m16] = (_Float16)p[nt][r];
        }
        __syncthreads();

        // O += P @ V
        #pragma unroll
        for (int kp = 0; kp < 2; kp++) {
            half8 pa = *(const half8*)(pw + m16 * 72 + kp * 32 + quad * 8);
            #pragma unroll
            for (int nt = 0; nt < 8; nt++) {
                half8 bfrag = *(const half8*)(vls + (nt * 16 + m16) * 72 + kp * 32 + quad * 8);
                acc[nt] = __builtin_amdgcn_mfma_f32_16x16x32_f16(pa, bfrag, acc[nt], 0, 0, 0);
            }
        }
        __syncthreads();
    }

    // epilogue: normalize and store fp32
    #pragma unroll
    for (int r = 0; r < 4; r++) {
        float inv_l = 1.0f / l_i[r];
        int row = b * 2048 + q0 + w * 16 + quad * 4 + r;
        float* dst = out + (size_t)row * 128;
        #pragma unroll
        for (int nt = 0; nt < 8; nt++)
            dst[nt * 16 + m16] = acc[nt][r] * inv_l;
    }
}

extern "C" void kernel_launch(void* const* d_in, const int* in_sizes, int n_in,
                              void* d_out, int out_size, void* d_ws, size_t ws_size,
                              hipStream_t stream) {
    const float* q   = (const float*)d_in[0];
    const float* k   = (const float*)d_in[1];
    const float* v   = (const float*)d_in[2];
    const int* mlen  = (const int*)d_in[3];
    const float* Wq  = (const float*)d_in[4];
    const float* Wk  = (const float*)d_in[5];
    const float* Wv  = (const float*)d_in[6];
    float* out = (float*)d_out;

    char* ws = (char*)d_ws;
    _Float16* wt = (_Float16*)(ws + OFF_WT);
    _Float16* qs = (_Float16*)(ws + OFF_QS);
    _Float16* kss = (_Float16*)(ws + OFF_KS);
    _Float16* vt = (_Float16*)(ws + OFF_VT);

    hipLaunchKernelGGL(wprep_kernel, dim3(1536), dim3(256), 0, stream, Wq, Wk, Wv, wt);
    hipLaunchKernelGGL(proj_kernel, dim3(256, 3), dim3(256), 0, stream,
                       q, k, v, wt, qs, kss, vt);
    hipLaunchKernelGGL(attn_kernel, dim3(32, 8), dim3(256), 0, stream,
                       qs, kss, vt, mlen, out);
}